// Round 2
// baseline (109.234 us; speedup 1.0000x reference)
//
#include <hip/hip_runtime.h>
#include <hip/hip_bf16.h>

// Problem constants (B,N,D,H,K) = (8,128,256,128,8) — all buffers fp32 per reference
#define PB 8
#define PN 128
#define PD 256
#define PH 128
#define PK 8

// Kernel 1: Ai' = E @ W1a^T + b1, Aj = E @ W1b^T  (fp32, per (b,n) block)
// plus K extra blocks computing Wq[h,k] = sum_d W2[d,h]*q[k,d], bq[k] = sum_d b2[d]*q[k,d]
__global__ __launch_bounds__(256) void k1_proj(
        const float* __restrict__ E, const float* __restrict__ W1,
        const float* __restrict__ b1, const float* __restrict__ W2,
        const float* __restrict__ b2, const float* __restrict__ q,
        float* __restrict__ Ai, float* __restrict__ Aj,
        float* __restrict__ Wq, float* __restrict__ bq)
{
    const int blk = blockIdx.x;
    const int t = threadIdx.x;

    if (blk < PB * PN) {
        __shared__ float es[PD];
        es[t] = E[blk * PD + t];           // stage the E row
        __syncthreads();

        const int h = t & (PH - 1);
        const int part = t >> 7;           // 0 -> Ai (with b1), 1 -> Aj
        const float* wrow = W1 + h * (2 * PD) + part * PD;

        float acc = 0.f;
        #pragma unroll 4
        for (int d0 = 0; d0 < PD; d0 += 8) {
            float w[8], e[8];
            *reinterpret_cast<float4*>(&w[0]) = *reinterpret_cast<const float4*>(wrow + d0);
            *reinterpret_cast<float4*>(&w[4]) = *reinterpret_cast<const float4*>(wrow + d0 + 4);
            *reinterpret_cast<float4*>(&e[0]) = *reinterpret_cast<const float4*>(&es[d0]);
            *reinterpret_cast<float4*>(&e[4]) = *reinterpret_cast<const float4*>(&es[d0 + 4]);
            #pragma unroll
            for (int r = 0; r < 8; ++r) acc = fmaf(w[r], e[r], acc);
        }
        if (part == 0) Ai[blk * PH + h] = acc + b1[h];
        else           Aj[blk * PH + h] = acc;
    } else {
        // Wq / bq blocks: one block per k
        const int k = blk - PB * PN;
        __shared__ float qs[PD];
        __shared__ float red[256];
        qs[t] = q[k * PD + t];
        __syncthreads();

        if (t < PH) {
            float acc = 0.f;
            for (int d = 0; d < PD; ++d)
                acc = fmaf(W2[d * PH + t], qs[d], acc);   // coalesced over t
            Wq[t * PK + k] = acc;
        }
        red[t] = b2[t] * qs[t];
        __syncthreads();
        for (int s = 128; s > 0; s >>= 1) {
            if (t < s) red[t] += red[t + s];
            __syncthreads();
        }
        if (t == 0) bq[k] = red[0];
    }
}

// Kernel 2: out[b,k,i,j] = sigmoid( sum_h relu(Ai'[b,i,h]+Aj[b,j,h]) * Wq[h,k] + bq[k] ) * (i!=j)
// block = (b,i), thread = j
__global__ __launch_bounds__(128) void k2_score(
        const float* __restrict__ Ai, const float* __restrict__ Aj,
        const float* __restrict__ Wq, const float* __restrict__ bq,
        float* __restrict__ out)
{
    const int b = blockIdx.x >> 7;
    const int i = blockIdx.x & (PN - 1);
    const int j = threadIdx.x;

    const float* airow = Ai + (b * PN + i) * PH;   // wave-uniform
    const float* ajrow = Aj + (b * PN + j) * PH;   // per-thread

    float acc[PK];
    #pragma unroll
    for (int k = 0; k < PK; ++k) acc[k] = bq[k];

    #pragma unroll 2
    for (int h = 0; h < PH; h += 4) {
        float ai4[4], aj4[4];
        *reinterpret_cast<float4*>(ai4) = *reinterpret_cast<const float4*>(airow + h);
        *reinterpret_cast<float4*>(aj4) = *reinterpret_cast<const float4*>(ajrow + h);
        #pragma unroll
        for (int r = 0; r < 4; ++r) {
            float v = fmaxf(ai4[r] + aj4[r], 0.f);
            float w[8];
            *reinterpret_cast<float4*>(&w[0]) = *reinterpret_cast<const float4*>(Wq + (h + r) * PK);
            *reinterpret_cast<float4*>(&w[4]) = *reinterpret_cast<const float4*>(Wq + (h + r) * PK + 4);
            #pragma unroll
            for (int k = 0; k < PK; ++k) acc[k] = fmaf(v, w[k], acc[k]);
        }
    }

    #pragma unroll
    for (int k = 0; k < PK; ++k) {
        float s = 1.f / (1.f + __expf(-acc[k]));
        if (j == i) s = 0.f;                        // zero diagonal
        out[((b * PK + k) * PN + i) * PN + j] = s;
    }
}

extern "C" void kernel_launch(void* const* d_in, const int* in_sizes, int n_in,
                              void* d_out, int out_size, void* d_ws, size_t ws_size,
                              hipStream_t stream) {
    const float* E  = (const float*)d_in[0];
    const float* W1 = (const float*)d_in[1];
    const float* b1 = (const float*)d_in[2];
    const float* W2 = (const float*)d_in[3];
    const float* b2 = (const float*)d_in[4];
    const float* q  = (const float*)d_in[5];

    float* Ai = (float*)d_ws;                 // B*N*H fp32
    float* Aj = Ai + PB * PN * PH;            // B*N*H fp32
    float* Wq = Aj + PB * PN * PH;            // H*K fp32
    float* bq = Wq + PH * PK;                 // K fp32

    k1_proj<<<PB * PN + PK, 256, 0, stream>>>(E, W1, b1, W2, b2, q, Ai, Aj, Wq, bq);
    k2_score<<<PB * PN, 128, 0, stream>>>(Ai, Aj, Wq, bq, (float*)d_out);
}

// Round 3
// 107.512 us; speedup vs baseline: 1.0160x; 1.0160x over previous
//
#include <hip/hip_runtime.h>

// (B,N,D,H,K) = (8,128,256,128,8) — all fp32
#define PB 8
#define PN 128
#define PD 256
#define PH 128
#define PK 8
#define D2 (2*PD)  // 512
#define NT 4       // n-rows per k1 block

// t0: W1t[d][h] = W1[h][d] (d in [0,512)); blocks 512..519: Wq[h][k], bq[k]
__global__ __launch_bounds__(128) void t0_prep(
        const float* __restrict__ W1, const float* __restrict__ W2,
        const float* __restrict__ b2, const float* __restrict__ q,
        float* __restrict__ W1t, float* __restrict__ Wq, float* __restrict__ bq)
{
    const int blk = blockIdx.x, t = threadIdx.x;
    if (blk < D2) {
        W1t[blk * PH + t] = W1[t * D2 + blk];   // write coalesced over lane t=h
    } else {
        const int k = blk - D2;
        __shared__ float qs[PD];
        __shared__ float red[128];
        qs[t]       = q[k * PD + t];
        qs[t + 128] = q[k * PD + t + 128];
        __syncthreads();
        float acc = 0.f;
        #pragma unroll 4
        for (int d = 0; d < PD; ++d)
            acc = fmaf(W2[d * PH + t], qs[d], acc);   // coalesced over t=h
        Wq[t * PK + k] = acc;                          // Wq row-contiguous in k
        red[t] = b2[t] * qs[t] + b2[t + 128] * qs[t + 128];
        __syncthreads();
        for (int s = 64; s > 0; s >>= 1) { if (t < s) red[t] += red[t + s]; __syncthreads(); }
        if (t == 0) bq[k] = red[0];
    }
}

// k1: Ai[b][n][h] = E[b][n][:]·W1a[h][:] + b1[h];  Ajt[b][h][n] = E[b][n][:]·W1b[h][:]
// block = (b, 4 n-rows), 256 threads: t&127 = h, t>>7 = part. Lane-coalesced W1t loads,
// wave-uniform E values (scalar loads). No LDS.
__global__ __launch_bounds__(256) void k1_proj(
        const float* __restrict__ E, const float* __restrict__ W1t,
        const float* __restrict__ b1,
        float* __restrict__ Ai, float* __restrict__ Ajt)
{
    const int blk = blockIdx.x, t = threadIdx.x;
    const int b  = blk / (PN / NT);
    const int n0 = (blk % (PN / NT)) * NT;
    const int h = t & (PH - 1);
    const int part = t >> 7;

    const float* w = W1t + part * PD * PH + h;     // stride PH per d, lane-contiguous
    const float* e = E + (b * PN + n0) * PD;       // wave-uniform rows

    float acc[NT];
    #pragma unroll
    for (int n = 0; n < NT; ++n) acc[n] = 0.f;

    #pragma unroll 8
    for (int d = 0; d < PD; ++d) {
        const float wv = w[d * PH];
        #pragma unroll
        for (int n = 0; n < NT; ++n)
            acc[n] = fmaf(wv, e[n * PD + d], acc[n]);  // e[..] uniform -> s_load
    }

    if (part == 0) {
        const float bb = b1[h];
        #pragma unroll
        for (int n = 0; n < NT; ++n)
            Ai[(b * PN + n0 + n) * PH + h] = acc[n] + bb;   // coalesced over h
    } else {
        #pragma unroll
        for (int n = 0; n < NT; ++n)
            Ajt[(b * PH + h) * PN + n0 + n] = acc[n];       // j-major for k2
    }
}

// k2: out[b,k,i,j] = sigmoid( sum_h relu(Ai[b,i,h]+Ajt[b,h,j])*Wq[h,k] + bq[k] ) * (i!=j)
// block = (b, i-pair), 256 threads: t>>7 picks i, t&127 = j. Ajt loads coalesced over j;
// Ai/Wq/bq wave-uniform (scalar loads).
__global__ __launch_bounds__(256) void k2_score(
        const float* __restrict__ Ai, const float* __restrict__ Ajt,
        const float* __restrict__ Wq, const float* __restrict__ bq,
        float* __restrict__ out)
{
    const int blk = blockIdx.x, t = threadIdx.x;
    const int b = blk >> 6;
    const int i = ((blk & 63) << 1) + (t >> 7);
    const int j = t & (PN - 1);

    const float* ai = Ai + (b * PN + i) * PH;   // uniform per wave-pair
    const float* aj = Ajt + b * PH * PN + j;    // lane-contiguous per h

    float acc[PK];
    #pragma unroll
    for (int k = 0; k < PK; ++k) acc[k] = bq[k];

    #pragma unroll 4
    for (int h = 0; h < PH; ++h) {
        const float v = fmaxf(ai[h] + aj[h * PN], 0.f);
        #pragma unroll
        for (int k = 0; k < PK; ++k)
            acc[k] = fmaf(v, Wq[h * PK + k], acc[k]);   // Wq row -> s_load_dwordx8
    }

    #pragma unroll
    for (int k = 0; k < PK; ++k) {
        float s = __builtin_amdgcn_rcpf(1.f + __expf(-acc[k]));
        if (j == i) s = 0.f;
        out[((b * PK + k) * PN + i) * PN + j] = s;      // coalesced over j
    }
}

extern "C" void kernel_launch(void* const* d_in, const int* in_sizes, int n_in,
                              void* d_out, int out_size, void* d_ws, size_t ws_size,
                              hipStream_t stream) {
    const float* E  = (const float*)d_in[0];
    const float* W1 = (const float*)d_in[1];
    const float* b1 = (const float*)d_in[2];
    const float* W2 = (const float*)d_in[3];
    const float* b2 = (const float*)d_in[4];
    const float* q  = (const float*)d_in[5];

    float* Ai  = (float*)d_ws;                 // B*N*H
    float* Ajt = Ai + PB * PN * PH;            // B*H*N
    float* W1t = Ajt + PB * PN * PH;           // 2D*H
    float* Wq  = W1t + D2 * PH;                // H*K
    float* bq  = Wq + PH * PK;                 // K

    t0_prep<<<D2 + PK, 128, 0, stream>>>(W1, W2, b2, q, W1t, Wq, bq);
    k1_proj<<<PB * (PN / NT), 256, 0, stream>>>(E, W1t, b1, Ai, Ajt);
    k2_score<<<PB * PN / 2, 256, 0, stream>>>(Ai, Ajt, Wq, bq, (float*)d_out);
}

// Round 4
// 101.367 us; speedup vs baseline: 1.0776x; 1.0606x over previous
//
#include <hip/hip_runtime.h>

// (B,N,D,H,K) = (8,128,256,128,8) — all fp32
#define PB 8
#define PN 128
#define PD 256
#define PH 128
#define PK 8
#define D2 (2*PD)  // 512
#define NT 4       // n-rows per k1 block

// ---------------------------------------------------------------------------
// t0: blocks [0,64): LDS-tiled transpose W1t[d'][h] = W1[h][d'] (32x32 tiles,
//     coalesced both directions). blocks [64,72): Wq[h][k], bq[k].
// ---------------------------------------------------------------------------
__global__ __launch_bounds__(256) void t0_prep(
        const float* __restrict__ W1, const float* __restrict__ W2,
        const float* __restrict__ b2, const float* __restrict__ q,
        float* __restrict__ W1t, float* __restrict__ Wq, float* __restrict__ bq)
{
    const int blk = blockIdx.x, t = threadIdx.x;
    if (blk < 64) {
        __shared__ float tile[32][33];                 // +1 pad: conflict-free
        const int h0 = (blk >> 4) << 5;                // 4 tiles of h
        const int d0 = (blk & 15) << 5;                // 16 tiles of d
        const int tx = t & 31, ty = t >> 5;            // ty in [0,8)
        #pragma unroll
        for (int s = 0; s < 4; ++s)                    // read: lanes along d
            tile[ty + 8 * s][tx] = W1[(h0 + ty + 8 * s) * D2 + d0 + tx];
        __syncthreads();
        #pragma unroll
        for (int s = 0; s < 4; ++s)                    // write: lanes along h
            W1t[(d0 + ty + 8 * s) * PH + h0 + tx] = tile[tx][ty + 8 * s];
    } else {
        const int k = blk - 64;
        __shared__ float qs[PD];
        __shared__ float red[256];
        qs[t] = q[k * PD + t];
        __syncthreads();
        if (t < PH) {
            float acc = 0.f;
            #pragma unroll 4
            for (int d = 0; d < PD; ++d)
                acc = fmaf(W2[d * PH + t], qs[d], acc);   // coalesced over t=h
            Wq[t * PK + k] = acc;                          // [h][k], k-contig
        }
        red[t] = b2[t] * qs[t];
        __syncthreads();
        for (int s = 128; s > 0; s >>= 1) { if (t < s) red[t] += red[t + s]; __syncthreads(); }
        if (t == 0) bq[k] = red[0];
    }
}

// ---------------------------------------------------------------------------
// k1: block = (b, 4 n-rows), 256 threads: h = t&127, part = t>>7.
//   Ai[b][n][h]  = E[b][n][:]·W1a[h][:] + b1[h]   (part 0)
//   Ajt[b][h][n] = E[b][n][:]·W1b[h][:]           (part 1, float4 store)
// E rows staged in LDS (broadcast b128 reads); W1t loads lane-coalesced.
// ---------------------------------------------------------------------------
__global__ __launch_bounds__(256) void k1_proj(
        const float* __restrict__ E, const float* __restrict__ W1t,
        const float* __restrict__ b1,
        float* __restrict__ Ai, float* __restrict__ Ajt)
{
    __shared__ float es[NT][PD];                       // 4 KB
    const int blk = blockIdx.x, t = threadIdx.x;
    const int b  = blk >> 5;                           // 32 blocks per b
    const int n0 = (blk & 31) * NT;

    const float* erow = E + (b * PN + n0) * PD;
    #pragma unroll
    for (int n = 0; n < NT; ++n)                       // coalesced staging
        es[n][t] = erow[n * PD + t];
    __syncthreads();

    const int h = t & (PH - 1);
    const int part = t >> 7;
    const float* w = W1t + part * PD * PH + h;         // lane-contiguous per d

    float acc[NT] = {0.f, 0.f, 0.f, 0.f};
    #pragma unroll 4
    for (int d = 0; d < PD; d += 4) {
        float wv[4];
        #pragma unroll
        for (int r = 0; r < 4; ++r) wv[r] = w[(d + r) * PH];   // 4 coalesced dwords
        #pragma unroll
        for (int n = 0; n < NT; ++n) {
            float4 e4 = *reinterpret_cast<const float4*>(&es[n][d]); // b128 broadcast
            acc[n] = fmaf(wv[0], e4.x, acc[n]);
            acc[n] = fmaf(wv[1], e4.y, acc[n]);
            acc[n] = fmaf(wv[2], e4.z, acc[n]);
            acc[n] = fmaf(wv[3], e4.w, acc[n]);
        }
    }

    if (part == 0) {
        const float bb = b1[h];
        #pragma unroll
        for (int n = 0; n < NT; ++n)
            Ai[(b * PN + n0 + n) * PH + h] = acc[n] + bb;   // coalesced over h
    } else {
        float4 v = make_float4(acc[0], acc[1], acc[2], acc[3]);
        *reinterpret_cast<float4*>(&Ajt[(b * PH + h) * PN + n0]) = v; // 1 dwordx4
    }
}

// ---------------------------------------------------------------------------
// k2: block = (b, i-pair), 256 threads: i = i0 + (t>>7), j = t&127.
// Wq/bq/Ai rows staged in LDS (broadcast reads, b128 for Wq rows);
// Ajt read coalesced over lane j; fused sigmoid + diag-zero; coalesced stores.
// ---------------------------------------------------------------------------
__global__ __launch_bounds__(256) void k2_score(
        const float* __restrict__ Ai, const float* __restrict__ Ajt,
        const float* __restrict__ Wq, const float* __restrict__ bq,
        float* __restrict__ out)
{
    __shared__ float wq[PH * PK];                      // 4 KB, [h][k] 16B-aligned rows
    __shared__ float ais[2 * PH];                      // the block's two Ai rows
    __shared__ float bqs[PK];

    const int blk = blockIdx.x, t = threadIdx.x;
    const int b  = blk >> 6;
    const int i0 = (blk & 63) << 1;

    *reinterpret_cast<float4*>(&wq[t * 4]) =
        *reinterpret_cast<const float4*>(&Wq[t * 4]);              // coalesced f4
    ais[t] = Ai[(b * PN + i0) * PH + t];               // rows i0, i0+1 back-to-back
    if (t < PK) bqs[t] = bq[t];
    __syncthreads();

    const int half = t >> 7;                           // which i of the pair
    const int i = i0 + half;
    const int j = t & (PN - 1);
    const float* ail = ais + half * PH;
    const float* aj = Ajt + b * PH * PN + j;           // lane-contiguous per h

    float acc[PK];
    #pragma unroll
    for (int k = 0; k < PK; ++k) acc[k] = bqs[k];

    #pragma unroll 4
    for (int h = 0; h < PH; ++h) {
        const float v = fmaxf(ail[h] + aj[h * PN], 0.f);   // 1 ds_b32 + 1 global
        float4 w0 = *reinterpret_cast<const float4*>(&wq[h * PK]);     // ds_b128
        float4 w1 = *reinterpret_cast<const float4*>(&wq[h * PK + 4]); // ds_b128
        acc[0] = fmaf(v, w0.x, acc[0]); acc[1] = fmaf(v, w0.y, acc[1]);
        acc[2] = fmaf(v, w0.z, acc[2]); acc[3] = fmaf(v, w0.w, acc[3]);
        acc[4] = fmaf(v, w1.x, acc[4]); acc[5] = fmaf(v, w1.y, acc[5]);
        acc[6] = fmaf(v, w1.z, acc[6]); acc[7] = fmaf(v, w1.w, acc[7]);
    }

    #pragma unroll
    for (int k = 0; k < PK; ++k) {
        float s = 1.f / (1.f + __expf(-acc[k]));
        if (j == i) s = 0.f;
        out[((b * PK + k) * PN + i) * PN + j] = s;     // coalesced over j
    }
}

extern "C" void kernel_launch(void* const* d_in, const int* in_sizes, int n_in,
                              void* d_out, int out_size, void* d_ws, size_t ws_size,
                              hipStream_t stream) {
    const float* E  = (const float*)d_in[0];
    const float* W1 = (const float*)d_in[1];
    const float* b1 = (const float*)d_in[2];
    const float* W2 = (const float*)d_in[3];
    const float* b2 = (const float*)d_in[4];
    const float* q  = (const float*)d_in[5];

    float* Ai  = (float*)d_ws;                 // B*N*H
    float* Ajt = Ai + PB * PN * PH;            // B*H*N
    float* W1t = Ajt + PB * PN * PH;           // 2D*H
    float* Wq  = W1t + D2 * PH;                // H*K
    float* bq  = Wq + PH * PK;                 // K

    t0_prep<<<64 + PK, 256, 0, stream>>>(W1, W2, b2, q, W1t, Wq, bq);
    k1_proj<<<PB * (PN / NT), 256, 0, stream>>>(E, W1t, b1, Ai, Ajt);
    k2_score<<<PB * PN / 2, 256, 0, stream>>>(Ai, Ajt, Wq, bq, (float*)d_out);
}